// Round 1
// baseline (430.514 us; speedup 1.0000x reference)
//
#include <hip/hip_runtime.h>
#include <hip/hip_bf16.h>

#define TILE  8
#define PADP  10      // padded tile edge (TILE + 2 halo)
#define NPIX  100     // 10*10 valid padded pixels
#define NPIXP 104     // pixel dim padded to multiple of 4 for float4
#define YSTR  132     // ys channel-row stride (128 + 4 to break bank aliasing)

__global__ __launch_bounds__(256, 2)
void attn_conv_fused(const float* __restrict__ x, const float* __restrict__ Wc,
                     const float* __restrict__ bc, float* __restrict__ out) {
    __shared__ float xs[64 * NPIXP];   // [ci][pixel]  26,624 B
    __shared__ float ys[NPIX * YSTR];  // [pixel][ch]  52,800 B

    const int tid = threadIdx.x;
    const int b  = blockIdx.z;
    const int h0 = blockIdx.y * TILE;
    const int w0 = blockIdx.x * TILE;

    // ---------------- Phase A0: stage x tile (with halo) into LDS ----------
    const float* xb = x + b * (64 * 128 * 128);
    for (int idx = tid; idx < 64 * NPIXP; idx += 256) {
        int i = (int)(((unsigned)idx * 40330u) >> 22);   // idx / 104 (exact for idx<2^16-ish)
        int p = idx - i * NPIXP;
        float v = 0.f;
        if (p < NPIX) {
            int py = (p * 205) >> 11;                    // p / 10 (exact for p<2048)
            int px = p - py * 10;
            int gh = h0 + py - 1, gw = w0 + px - 1;
            if (gh >= 0 && gh < 128 && gw >= 0 && gw < 128)
                v = xb[(i << 14) + (gh << 7) + gw];
        }
        xs[idx] = v;
    }

    // ---------------- Phase A1: load Wc row + bias into registers ----------
    const int c = tid & 127;   // channel owned by this thread
    const int g = tid >> 7;    // pixel half: 0 or 1
    float w[64];
    {
        const float4* wrow = (const float4*)(Wc + c * 64);
        float4* wr = (float4*)w;
        #pragma unroll
        for (int k = 0; k < 16; ++k) wr[k] = wrow[k];
    }
    const float bias = bc[c];
    __syncthreads();

    // ---------------- Phase A2: 1x1 conv into ys[p][c] ---------------------
    // thread computes its channel for 52 pixels, 4 at a time (float4 LDS
    // reads are wave-uniform-address -> broadcast, conflict-free)
    const int pbase0 = g * 52;
    for (int p4 = 0; p4 < 13; ++p4) {
        const int pb = pbase0 + p4 * 4;
        float ax = bias, ay = bias, az = bias, aw = bias;
        const float* xcol = xs + pb;
        #pragma unroll
        for (int i = 0; i < 64; ++i) {
            float4 xv = *(const float4*)(xcol + i * NPIXP);
            ax += xv.x * w[i];
            ay += xv.y * w[i];
            az += xv.z * w[i];
            aw += xv.w * w[i];
        }
        float accv[4] = {ax, ay, az, aw};
        #pragma unroll
        for (int j = 0; j < 4; ++j) {
            int p = pb + j;
            if (p < NPIX) {
                int py = (p * 205) >> 11;
                int px = p - py * 10;
                int gh = h0 + py - 1, gw = w0 + px - 1;
                float v = accv[j];
                // attention pads y with zeros outside the image
                if (gh < 0 || gh >= 128 || gw < 0 || gw >= 128) v = 0.f;
                ys[p * YSTR + c] = v;
            }
        }
    }
    __syncthreads();

    // ---------------- Phase B: 3x3 local attention -------------------------
    const int q   = tid >> 2;        // output pixel 0..63
    const int sub = tid & 3;         // channel quarter
    const int oy  = q >> 3, ox = q & 7;
    const int pc  = (oy + 1) * PADP + (ox + 1);
    const float* ysc = ys + pc * YSTR + sub * 32;

    float4 ctr[8];
    #pragma unroll
    for (int k = 0; k < 8; ++k) ctr[k] = *(const float4*)(ysc + k * 4);

    float s[9];
    #pragma unroll
    for (int n = 0; n < 9; ++n) {
        const int dy = n / 3 - 1, dx = n % 3 - 1;
        const float* ysn = ys + (pc + dy * PADP + dx) * YSTR + sub * 32;
        float acc = 0.f;
        #pragma unroll
        for (int k = 0; k < 8; ++k) {
            float4 v = *(const float4*)(ysn + k * 4);
            acc += v.x * ctr[k].x + v.y * ctr[k].y + v.z * ctr[k].z + v.w * ctr[k].w;
        }
        s[n] = acc;
    }
    // reduce partial dots across the 4 channel-quarter lanes
    #pragma unroll
    for (int n = 0; n < 9; ++n) {
        s[n] += __shfl_xor(s[n], 1);
        s[n] += __shfl_xor(s[n], 2);
        s[n] *= 0.08838834764831845f;   // 1/sqrt(128)
    }
    // softmax over the 9 neighbors (computed redundantly by all 4 subs)
    float m = s[0];
    #pragma unroll
    for (int n = 1; n < 9; ++n) m = fmaxf(m, s[n]);
    float e[9], sum = 0.f;
    #pragma unroll
    for (int n = 0; n < 9; ++n) { e[n] = __expf(s[n] - m); sum += e[n]; }
    const float inv = 1.f / sum;

    float4 o[8];
    #pragma unroll
    for (int k = 0; k < 8; ++k) o[k] = make_float4(0.f, 0.f, 0.f, 0.f);
    #pragma unroll
    for (int n = 0; n < 9; ++n) {
        const float a = e[n] * inv;
        const int dy = n / 3 - 1, dx = n % 3 - 1;
        const float* ysn = ys + (pc + dy * PADP + dx) * YSTR + sub * 32;
        #pragma unroll
        for (int k = 0; k < 8; ++k) {
            float4 v = *(const float4*)(ysn + k * 4);
            o[k].x += a * v.x; o[k].y += a * v.y;
            o[k].z += a * v.z; o[k].w += a * v.w;
        }
    }

    // store out[b][c][h0+oy][w0+ox], c = sub*32 + 4k + j
    float* ob = out + ((size_t)(b * 128 + sub * 32) * 128 + (h0 + oy)) * 128 + (w0 + ox);
    #pragma unroll
    for (int k = 0; k < 8; ++k) {
        ob[(size_t)(k * 4 + 0) * 16384] = o[k].x;
        ob[(size_t)(k * 4 + 1) * 16384] = o[k].y;
        ob[(size_t)(k * 4 + 2) * 16384] = o[k].z;
        ob[(size_t)(k * 4 + 3) * 16384] = o[k].w;
    }
}

extern "C" void kernel_launch(void* const* d_in, const int* in_sizes, int n_in,
                              void* d_out, int out_size, void* d_ws, size_t ws_size,
                              hipStream_t stream) {
    const float* x  = (const float*)d_in[0];
    const float* Wc = (const float*)d_in[1];
    const float* bc = (const float*)d_in[2];
    float* out = (float*)d_out;

    dim3 grid(128 / TILE, 128 / TILE, 8);   // 16 x 16 x 8 = 2048 blocks
    dim3 block(256);
    attn_conv_fused<<<grid, block, 0, stream>>>(x, Wc, bc, out);
}

// Round 2
// 137.849 us; speedup vs baseline: 3.1231x; 3.1231x over previous
//
#include <hip/hip_runtime.h>
#include <hip/hip_bf16.h>

typedef __attribute__((ext_vector_type(8))) short short8;   // 8 x bf16 (4 VGPRs)
typedef __attribute__((ext_vector_type(4))) float floatx4;  // MFMA acc

#define XS_STRIDE 72    // ushorts; 144B rows -> A-frag bank spread (m + quad) % 8
#define YS_STRIDE 128   // ushorts; 256B rows; attention reads spread by g
#define OST_STRIDE 132  // floats; coop reads 2-way (free)
// smem map: xs [204][72] = 29376 B  (reused as ostage [32][132] = 16896 B)
//           ys [204][128] = 52224 B ; total 81600 B -> 2 blocks/CU

__device__ __forceinline__ ushort f2bf(float f) {
    union { __hip_bfloat16 h; ushort u; } cv;
    cv.h = __float2bfloat16(f);
    return cv.u;
}
__device__ __forceinline__ float bflo(unsigned int u) { return __uint_as_float(u << 16); }
__device__ __forceinline__ float bfhi(unsigned int u) { return __uint_as_float(u & 0xffff0000u); }

__device__ __forceinline__ float dot8(uint4 p, const float* cf) {
    return bflo(p.x)*cf[0] + bfhi(p.x)*cf[1] + bflo(p.y)*cf[2] + bfhi(p.y)*cf[3]
         + bflo(p.z)*cf[4] + bfhi(p.z)*cf[5] + bflo(p.w)*cf[6] + bfhi(p.w)*cf[7];
}
__device__ __forceinline__ void fma8(uint4 p, float a, float* o) {
    o[0] += a*bflo(p.x); o[1] += a*bfhi(p.x); o[2] += a*bflo(p.y); o[3] += a*bfhi(p.y);
    o[4] += a*bflo(p.z); o[5] += a*bfhi(p.z); o[6] += a*bflo(p.w); o[7] += a*bfhi(p.w);
}

__global__ __launch_bounds__(256, 2)
void attn_conv_fused(const float* __restrict__ x, const float* __restrict__ Wc,
                     const float* __restrict__ bc, float* __restrict__ out) {
    __shared__ __align__(16) unsigned char smem[81600];
    ushort* xs = (ushort*)smem;               // [204][72] bf16, X transposed [px][ci]
    float*  ostage = (float*)smem;            // [32][132] f32 (reuses xs space)
    ushort* ys = (ushort*)(smem + 29376);     // [204][128] bf16, Y [px][c]

    const int tid = threadIdx.x;
    const int b  = blockIdx.z;
    const int h0 = blockIdx.y * 4;
    const int w0 = blockIdx.x * 32;
    const int lane = tid & 63;
    const int wv   = tid >> 6;

    // ---------------- Phase A0: stage x tile transposed -> xs[px][ci] bf16 ----
    if (tid < 204) {
        int py  = (tid * 965) >> 15;          // tid / 34 (exact for tid<208)
        int pxx = tid - py * 34;
        int gh = h0 + py - 1, gw = w0 + pxx - 1;
        bool inb = (gh >= 0 && gh < 128 && gw >= 0 && gw < 128);
        ushort* dst = xs + tid * XS_STRIDE;
        if (inb) {
            const float* xp = x + (b * 64) * 16384 + gh * 128 + gw;
            #pragma unroll
            for (int c0 = 0; c0 < 64; c0 += 4) {
                float v0 = xp[(c0 + 0) << 14];
                float v1 = xp[(c0 + 1) << 14];
                float v2 = xp[(c0 + 2) << 14];
                float v3 = xp[(c0 + 3) << 14];
                unsigned int u01 = (unsigned int)f2bf(v0) | ((unsigned int)f2bf(v1) << 16);
                unsigned int u23 = (unsigned int)f2bf(v2) | ((unsigned int)f2bf(v3) << 16);
                *(uint2*)(dst + c0) = make_uint2(u01, u23);
            }
        } else {
            #pragma unroll
            for (int c0 = 0; c0 < 64; c0 += 4)
                *(uint2*)(dst + c0) = make_uint2(0u, 0u);
        }
    }

    // ---------------- Phase A1: W fragments (B-operand) from global ----------
    // B[k][n]: lane holds n = lane&15 (channel-in-tile), k = (lane>>4)*8 + j
    const int col = lane & 15;
    const int kq  = lane >> 4;
    short8 bw[8][2];
    float  bias[8];
    #pragma unroll
    for (int t = 0; t < 8; ++t) {
        int c = t * 16 + col;
        bias[t] = bc[c];
        #pragma unroll
        for (int half = 0; half < 2; ++half) {
            const float* wp = Wc + c * 64 + half * 32 + kq * 8;
            float4 wa = *(const float4*)wp;
            float4 wb = *(const float4*)(wp + 4);
            short8 f;
            f[0] = (short)f2bf(wa.x); f[1] = (short)f2bf(wa.y);
            f[2] = (short)f2bf(wa.z); f[3] = (short)f2bf(wa.w);
            f[4] = (short)f2bf(wb.x); f[5] = (short)f2bf(wb.y);
            f[6] = (short)f2bf(wb.z); f[7] = (short)f2bf(wb.w);
            bw[t][half] = f;
        }
    }
    __syncthreads();

    // ---------------- Phase A2: MFMA conv Y[204px][128c] = X·W^T -------------
    // A[m][k]: lane reads m = lane&15, k-chunk = (lane>>4)*8; D: col=lane&15, row=(lane>>4)*4+r
    for (int mt = wv; mt < 13; mt += 4) {
        int pxa = mt * 16 + col;              // A-row pixel this lane reads
        const ushort* ap = xs + pxa * XS_STRIDE + kq * 8;
        short8 a0 = *(const short8*)(ap);          // k 0..31 slice
        short8 a1 = *(const short8*)(ap + 32);     // k 32..63 slice
        floatx4 acc[8];
        #pragma unroll
        for (int t = 0; t < 8; ++t) acc[t] = (floatx4){0.f, 0.f, 0.f, 0.f};
        #pragma unroll
        for (int t = 0; t < 8; ++t) {
            acc[t] = __builtin_amdgcn_mfma_f32_16x16x32_bf16(a0, bw[t][0], acc[t], 0, 0, 0);
            acc[t] = __builtin_amdgcn_mfma_f32_16x16x32_bf16(a1, bw[t][1], acc[t], 0, 0, 0);
        }
        #pragma unroll
        for (int r = 0; r < 4; ++r) {
            int pxr = mt * 16 + kq * 4 + r;   // D row = (lane>>4)*4 + r
            if (pxr < 204) {
                int py  = (pxr * 965) >> 15;
                int pxx = pxr - py * 34;
                int gh = h0 + py - 1, gw = w0 + pxx - 1;
                bool inb = (gh >= 0 && gh < 128 && gw >= 0 && gw < 128);
                ushort* yrow = ys + pxr * YS_STRIDE + col;
                #pragma unroll
                for (int t = 0; t < 8; ++t)
                    yrow[t * 16] = f2bf(inb ? (acc[t][r] + bias[t]) : 0.f);
            }
        }
    }
    __syncthreads();

    // ---------------- Phase B: 3x3 local attention, one row per pass ---------
    const int g  = tid & 7;                   // channel group: c0 = g*16
    const int ox = tid >> 3;                  // 0..31
    for (int oy = 0; oy < 4; ++oy) {
        int pc = (oy + 1) * 34 + (ox + 1);
        const ushort* base = ys + g * 16;
        uint4 plo[9], phi[9];
        #pragma unroll
        for (int n = 0; n < 9; ++n) {
            int pi = pc + (n / 3 - 1) * 34 + (n % 3 - 1);
            const ushort* pp = base + pi * YS_STRIDE;
            plo[n] = *(const uint4*)pp;
            phi[n] = *(const uint4*)(pp + 8);
        }
        float cf[16];
        {
            uint4 c0 = plo[4], c1 = phi[4];
            cf[0]=bflo(c0.x); cf[1]=bfhi(c0.x); cf[2]=bflo(c0.y); cf[3]=bfhi(c0.y);
            cf[4]=bflo(c0.z); cf[5]=bfhi(c0.z); cf[6]=bflo(c0.w); cf[7]=bfhi(c0.w);
            cf[8]=bflo(c1.x); cf[9]=bfhi(c1.x); cf[10]=bflo(c1.y); cf[11]=bfhi(c1.y);
            cf[12]=bflo(c1.z); cf[13]=bfhi(c1.z); cf[14]=bflo(c1.w); cf[15]=bfhi(c1.w);
        }
        float s[9];
        #pragma unroll
        for (int n = 0; n < 9; ++n)
            s[n] = dot8(plo[n], cf) + dot8(phi[n], cf + 8);
        #pragma unroll
        for (int n = 0; n < 9; ++n) {
            s[n] += __shfl_xor(s[n], 1);
            s[n] += __shfl_xor(s[n], 2);
            s[n] += __shfl_xor(s[n], 4);
            s[n] *= 0.08838834764831845f;     // 1/sqrt(128)
        }
        float m = s[0];
        #pragma unroll
        for (int n = 1; n < 9; ++n) m = fmaxf(m, s[n]);
        float e[9], sum = 0.f;
        #pragma unroll
        for (int n = 0; n < 9; ++n) { e[n] = __expf(s[n] - m); sum += e[n]; }
        float inv = 1.f / sum;

        float o[16];
        #pragma unroll
        for (int j = 0; j < 16; ++j) o[j] = 0.f;
        #pragma unroll
        for (int n = 0; n < 9; ++n) {
            float a = e[n] * inv;
            fma8(plo[n], a, o);
            fma8(phi[n], a, o + 8);
        }

        // stage to ostage[ox][c] for coalesced global store
        float* op = ostage + ox * OST_STRIDE + g * 16;
        #pragma unroll
        for (int k = 0; k < 4; ++k)
            *(float4*)(op + 4 * k) = make_float4(o[4*k], o[4*k+1], o[4*k+2], o[4*k+3]);
        __syncthreads();

        // cooperative store: full 128B line per (c,row)
        {
            int c = tid >> 1, half = tid & 1;
            float tmp[16];
            #pragma unroll
            for (int j = 0; j < 16; ++j)
                tmp[j] = ostage[(half * 16 + j) * OST_STRIDE + c];
            float* og = out + ((size_t)((b * 128 + c) * 128 + (h0 + oy))) * 128 + w0 + half * 16;
            #pragma unroll
            for (int k = 0; k < 4; ++k)
                *(float4*)(og + 4 * k) = make_float4(tmp[4*k], tmp[4*k+1], tmp[4*k+2], tmp[4*k+3]);
        }
        __syncthreads();
    }
}

extern "C" void kernel_launch(void* const* d_in, const int* in_sizes, int n_in,
                              void* d_out, int out_size, void* d_ws, size_t ws_size,
                              hipStream_t stream) {
    const float* x  = (const float*)d_in[0];
    const float* Wc = (const float*)d_in[1];
    const float* bc = (const float*)d_in[2];
    float* out = (float*)d_out;

    dim3 grid(4, 32, 8);     // 32w x 4h tiles: 4 x 32 x 8 = 1024 blocks
    dim3 block(256);
    attn_conv_fused<<<grid, block, 0, stream>>>(x, Wc, bc, out);
}